// Round 1
// baseline (125.782 us; speedup 1.0000x reference)
//
#include <hip/hip_runtime.h>

// ---------------------------------------------------------------------------
// SimpleAttention: out[b,h,w,d] = softmax_bhw( x^T (WqWk^T) x ) * (x . rowsum(Wv)) * Wo[d] + bo[d]
// Reduced to: prep(M=Wq@Wk^T split bf16 hi/lo) -> score GEMM (MFMA, 3-segment
// split precision) -> per-batch softmax stats -> rank-1 output write.
// ---------------------------------------------------------------------------

typedef __bf16 bf16_t;
typedef __attribute__((ext_vector_type(8))) __bf16 bf16x8;
typedef __attribute__((ext_vector_type(4))) __bf16 bf16x4;
typedef __attribute__((ext_vector_type(4))) float f32x4;

#define NBATCH 16
#define CCH    256
#define NPIX   65536      // 16*64*64
#define PPB    4096       // pixels per batch (softmax group)

// ws byte offsets (total ~789 KB needed)
#define MH_OFF    0u
#define ML_OFF    131072u
#define U_OFF     262144u
#define WV_OFF    263168u
#define SCL_OFF   264192u   // [0]=c0 (bq.bk), [1]=bvs (sum bv)
#define SCORE_OFF 264448u
#define SV_OFF    526592u
#define BMAX_OFF  788736u
#define BSUM_OFF  788800u

// ---------------------------------------------------------------------------
// prep: blocks 0..255 compute M[c][c'] = Wq[c,:].Wk[c',:], split to bf16 hi/lo.
// block 256 computes u = Wq@bk + Wk@bq, wv = rowsum(Wv), c0 = bq.bk, bvs = sum(bv).
// ---------------------------------------------------------------------------
__global__ __launch_bounds__(256) void prep_kernel(
    const float* __restrict__ Wq, const float* __restrict__ bq,
    const float* __restrict__ Wk, const float* __restrict__ bk,
    const float* __restrict__ Wv, const float* __restrict__ bv,
    bf16_t* __restrict__ Mh, bf16_t* __restrict__ Ml,
    float* __restrict__ u, float* __restrict__ wv, float* __restrict__ scl)
{
    const int t = threadIdx.x;
    if (blockIdx.x < 256) {
        const int c = blockIdx.x;
        __shared__ __align__(16) float wq_row[256];
        wq_row[t] = Wq[c * 256 + t];
        __syncthreads();
        const float4* wk4 = (const float4*)(Wk + t * 256);
        const float4* wq4 = (const float4*)wq_row;
        float acc = 0.f;
#pragma unroll 8
        for (int i = 0; i < 64; ++i) {
            float4 a = wq4[i], b = wk4[i];
            acc += a.x * b.x + a.y * b.y + a.z * b.z + a.w * b.w;
        }
        bf16_t h = (bf16_t)acc;
        float hf = (float)h;
        bf16_t l = (bf16_t)(acc - hf);
        Mh[c * 256 + t] = h;
        Ml[c * 256 + t] = l;
    } else {
        float uacc = 0.f, wvacc = 0.f;
        const float* wqr = Wq + t * 256;
        const float* wkr = Wk + t * 256;
        const float* wvr = Wv + t * 256;
#pragma unroll 4
        for (int d = 0; d < 256; ++d) {
            uacc += wqr[d] * bk[d] + wkr[d] * bq[d];
            wvacc += wvr[d];
        }
        u[t] = uacc;
        wv[t] = wvacc;
        __shared__ float r1[256], r2[256];
        r1[t] = bq[t] * bk[t];
        r2[t] = bv[t];
        __syncthreads();
        for (int s = 128; s > 0; s >>= 1) {
            if (t < s) { r1[t] += r1[t + s]; r2[t] += r2[t + s]; }
            __syncthreads();
        }
        if (t == 0) { scl[0] = r1[0]; scl[1] = r2[0]; }
    }
}

// ---------------------------------------------------------------------------
// score kernel: per block, 128 pixels. Y = Xsplit @ Msplit (3 segments, K=256
// each), then score[p] = x_p . (Y_p + u) + c0, sv[p] = x_p . wv + bvs.
// 4 waves; wave w owns cols [w*64, w*64+64). A (xh/xl chunk) staged in padded
// LDS; B fragments read directly from L2-resident M (each block reads M once).
// ---------------------------------------------------------------------------
__global__ __launch_bounds__(256) void score_kernel(
    const float* __restrict__ x,
    const bf16_t* __restrict__ Mh, const bf16_t* __restrict__ Ml,
    const float* __restrict__ u, const float* __restrict__ wvp,
    const float* __restrict__ scl,
    float* __restrict__ score, float* __restrict__ svout)
{
    __shared__ __align__(16) bf16_t Ah[128][72];   // +8 pad: ~2-way banks on b128
    __shared__ __align__(16) bf16_t Al[128][72];
    __shared__ float redS[4][128];
    __shared__ float redV[4][128];

    const int t = threadIdx.x;
    const int lane = t & 63;
    const int wid = t >> 6;        // wave 0..3
    const int l15 = lane & 15;
    const int lg = lane >> 4;      // 0..3
    const int pix0 = blockIdx.x * 128;
    const int wcol0 = wid * 64;

    f32x4 acc[8][4];
#pragma unroll
    for (int i = 0; i < 8; ++i)
#pragma unroll
        for (int j = 0; j < 4; ++j)
            acc[i][j] = (f32x4){0.f, 0.f, 0.f, 0.f};

    for (int kc = 0; kc < 4; ++kc) {
        const int k0 = kc * 64;
        __syncthreads();  // protect previous chunk's LDS reads
        // stage x[pix0..pix0+128)[k0..k0+64) as bf16 hi/lo into LDS
#pragma unroll
        for (int i = 0; i < 8; ++i) {
            int li = i * 256 + t;
            int r = li >> 4;
            int c4 = (li & 15) << 2;
            float4 xv = *(const float4*)(x + (size_t)(pix0 + r) * 256 + k0 + c4);
            bf16x4 hi, lo;
            hi[0] = (bf16_t)xv.x; hi[1] = (bf16_t)xv.y;
            hi[2] = (bf16_t)xv.z; hi[3] = (bf16_t)xv.w;
            lo[0] = (bf16_t)(xv.x - (float)hi[0]);
            lo[1] = (bf16_t)(xv.y - (float)hi[1]);
            lo[2] = (bf16_t)(xv.z - (float)hi[2]);
            lo[3] = (bf16_t)(xv.w - (float)hi[3]);
            *(bf16x4*)&Ah[r][c4] = hi;
            *(bf16x4*)&Al[r][c4] = lo;
        }
        __syncthreads();
#pragma unroll
        for (int seg = 0; seg < 3; ++seg) {
            const bf16_t* Bsrc = (seg == 2) ? Ml : Mh;
#pragma unroll
            for (int ks = 0; ks < 2; ++ks) {
                const int kk = ks * 32;
                bf16x8 af[8];
#pragma unroll
                for (int rf = 0; rf < 8; ++rf) {
                    const bf16_t* ap = (seg == 1) ? &Al[rf * 16 + l15][kk + lg * 8]
                                                  : &Ah[rf * 16 + l15][kk + lg * 8];
                    af[rf] = *(const bf16x8*)ap;
                }
                bf16x8 bfr[4];
#pragma unroll
                for (int cf = 0; cf < 4; ++cf) {
                    int col = wcol0 + cf * 16 + l15;
                    bfr[cf] = *(const bf16x8*)(Bsrc + (size_t)col * 256 + k0 + kk + lg * 8);
                }
#pragma unroll
                for (int rf = 0; rf < 8; ++rf)
#pragma unroll
                    for (int cf = 0; cf < 4; ++cf)
                        acc[rf][cf] = __builtin_amdgcn_mfma_f32_16x16x32_bf16(
                            af[rf], bfr[cf], acc[rf][cf], 0, 0, 0);
            }
        }
    }

    // epilogue: score_p = sum_n x[p,n]*(Y[p,n]+u[n]); sv_p = sum_n x[p,n]*wv[n]
    float uu[4], wvl[4];
#pragma unroll
    for (int cf = 0; cf < 4; ++cf) {
        uu[cf] = u[wcol0 + cf * 16 + l15];
        wvl[cf] = wvp[wcol0 + cf * 16 + l15];
    }
#pragma unroll
    for (int rf = 0; rf < 8; ++rf) {
#pragma unroll
        for (int r = 0; r < 4; ++r) {
            int row = rf * 16 + lg * 4 + r;   // C layout: col=lane&15, row=(lane>>4)*4+reg
            const float* xr = x + (size_t)(pix0 + row) * 256 + wcol0 + l15;
            float s = 0.f, v = 0.f;
#pragma unroll
            for (int cf = 0; cf < 4; ++cf) {
                float xv = xr[cf * 16];
                s += xv * (acc[rf][cf][r] + uu[cf]);
                v += xv * wvl[cf];
            }
#pragma unroll
            for (int m = 1; m < 16; m <<= 1) {
                s += __shfl_xor(s, m, 64);
                v += __shfl_xor(v, m, 64);
            }
            if (l15 == 0) { redS[wid][row] = s; redV[wid][row] = v; }
        }
    }
    __syncthreads();
    if (t < 128) {
        float c0 = scl[0], bvs = scl[1];
        float s = redS[0][t] + redS[1][t] + redS[2][t] + redS[3][t] + c0;
        float v = redV[0][t] + redV[1][t] + redV[2][t] + redV[3][t] + bvs;
        score[pix0 + t] = s;
        svout[pix0 + t] = v;
    }
}

// ---------------------------------------------------------------------------
// per-batch softmax stats over 4096 pixels
// ---------------------------------------------------------------------------
__global__ __launch_bounds__(256) void stats_kernel(
    const float* __restrict__ score,
    float* __restrict__ bmax, float* __restrict__ bsum)
{
    const int b = blockIdx.x, t = threadIdx.x;
    const float* s = score + b * PPB;
    __shared__ float red[256];
    float m = -1e30f;
    for (int i = t; i < PPB; i += 256) m = fmaxf(m, s[i]);
    red[t] = m;
    __syncthreads();
    for (int k = 128; k > 0; k >>= 1) {
        if (t < k) red[t] = fmaxf(red[t], red[t + k]);
        __syncthreads();
    }
    m = red[0];
    __syncthreads();
    float sum = 0.f;
    for (int i = t; i < PPB; i += 256) sum += __expf(s[i] - m);
    red[t] = sum;
    __syncthreads();
    for (int k = 128; k > 0; k >>= 1) {
        if (t < k) red[t] += red[t + k];
        __syncthreads();
    }
    if (t == 0) { bmax[b] = m; bsum[b] = red[0]; }
}

// ---------------------------------------------------------------------------
// output: out[p, 0:256] = g_p * Wo + bo,  g_p = softmax(score)_p * sv_p
// ---------------------------------------------------------------------------
__global__ __launch_bounds__(256) void out_kernel(
    const float* __restrict__ score, const float* __restrict__ sv,
    const float* __restrict__ bmax, const float* __restrict__ bsum,
    const float* __restrict__ Wo, const float* __restrict__ bo,
    float* __restrict__ out)
{
    const int total = NPIX * 64;  // float4 count
    const int stride = gridDim.x * blockDim.x;
    for (int idx = blockIdx.x * blockDim.x + threadIdx.x; idx < total; idx += stride) {
        int p = idx >> 6;
        int c4 = (idx & 63) << 2;
        int b = p >> 12;
        float g = __expf(score[p] - bmax[b]) / bsum[b] * sv[p];
        float4 w = *(const float4*)(Wo + c4);
        float4 bb = *(const float4*)(bo + c4);
        float4 o = { g * w.x + bb.x, g * w.y + bb.y, g * w.z + bb.z, g * w.w + bb.w };
        *(float4*)(out + (size_t)p * 256 + c4) = o;
    }
}

extern "C" void kernel_launch(void* const* d_in, const int* in_sizes, int n_in,
                              void* d_out, int out_size, void* d_ws, size_t ws_size,
                              hipStream_t stream) {
    const float* x  = (const float*)d_in[0];
    const float* Wq = (const float*)d_in[1];
    const float* bq = (const float*)d_in[2];
    const float* Wk = (const float*)d_in[3];
    const float* bk = (const float*)d_in[4];
    const float* Wv = (const float*)d_in[5];
    const float* bv = (const float*)d_in[6];
    const float* Wo = (const float*)d_in[7];
    const float* bo = (const float*)d_in[8];
    float* out = (float*)d_out;
    char* ws = (char*)d_ws;

    bf16_t* Mh = (bf16_t*)(ws + MH_OFF);
    bf16_t* Ml = (bf16_t*)(ws + ML_OFF);
    float* u   = (float*)(ws + U_OFF);
    float* wv  = (float*)(ws + WV_OFF);
    float* scl = (float*)(ws + SCL_OFF);
    float* score = (float*)(ws + SCORE_OFF);
    float* sv    = (float*)(ws + SV_OFF);
    float* bmax  = (float*)(ws + BMAX_OFF);
    float* bsum  = (float*)(ws + BSUM_OFF);

    prep_kernel<<<dim3(257), dim3(256), 0, stream>>>(Wq, bq, Wk, bk, Wv, bv, Mh, Ml, u, wv, scl);
    score_kernel<<<dim3(NPIX / 128), dim3(256), 0, stream>>>(x, Mh, Ml, u, wv, scl, score, sv);
    stats_kernel<<<dim3(NBATCH), dim3(256), 0, stream>>>(score, bmax, bsum);
    out_kernel<<<dim3(2048), dim3(256), 0, stream>>>(score, sv, bmax, bsum, Wo, bo, out);
}

// Round 2
// 102.589 us; speedup vs baseline: 1.2261x; 1.2261x over previous
//
#include <hip/hip_runtime.h>

// ---------------------------------------------------------------------------
// SimpleAttention: out[b,h,w,d] = softmax_bhw( x^T (WqWk^T) x ) * (x . rowsum(Wv)) * Wo[d] + bo[d]
// prep(M=Wq@Wk^T split bf16 hi/lo) -> score GEMM (MFMA, 3-segment split
// precision, full-K LDS tile, swizzled) -> per-batch softmax stats -> rank-1 out.
// ---------------------------------------------------------------------------

typedef __bf16 bf16_t;
typedef __attribute__((ext_vector_type(8))) __bf16 bf16x8;
typedef __attribute__((ext_vector_type(4))) __bf16 bf16x4;
typedef __attribute__((ext_vector_type(4))) float f32x4;

#define NBATCH 16
#define NPIX   65536      // 16*64*64
#define PPB    4096       // pixels per batch (softmax group)

// ws byte offsets
#define MH_OFF    0u
#define ML_OFF    131072u
#define U_OFF     262144u
#define WV_OFF    263168u
#define SCL_OFF   264192u   // [0]=c0 (bq.bk), [1]=bvs (sum bv)
#define SCORE_OFF 264448u
#define SV_OFF    526592u
#define BMAX_OFF  788736u
#define BSUM_OFF  788800u

// ---------------------------------------------------------------------------
// prep: blocks 0..255 compute M[c][c'] = Wq[c,:].Wk[c',:], split to bf16 hi/lo.
// block 256 computes u = Wq@bk + Wk@bq, wv = rowsum(Wv), c0 = bq.bk, bvs = sum(bv).
// ---------------------------------------------------------------------------
__global__ __launch_bounds__(256) void prep_kernel(
    const float* __restrict__ Wq, const float* __restrict__ bq,
    const float* __restrict__ Wk, const float* __restrict__ bk,
    const float* __restrict__ Wv, const float* __restrict__ bv,
    bf16_t* __restrict__ Mh, bf16_t* __restrict__ Ml,
    float* __restrict__ u, float* __restrict__ wv, float* __restrict__ scl)
{
    const int t = threadIdx.x;
    if (blockIdx.x < 256) {
        const int c = blockIdx.x;
        __shared__ __align__(16) float wq_row[256];
        wq_row[t] = Wq[c * 256 + t];
        __syncthreads();
        const float4* wk4 = (const float4*)(Wk + t * 256);
        const float4* wq4 = (const float4*)wq_row;
        float acc = 0.f;
#pragma unroll 8
        for (int i = 0; i < 64; ++i) {
            float4 a = wq4[i], b = wk4[i];
            acc += a.x * b.x + a.y * b.y + a.z * b.z + a.w * b.w;
        }
        bf16_t h = (bf16_t)acc;
        float hf = (float)h;
        bf16_t l = (bf16_t)(acc - hf);
        Mh[c * 256 + t] = h;
        Ml[c * 256 + t] = l;
    } else {
        float uacc = 0.f, wvacc = 0.f;
        const float* wqr = Wq + t * 256;
        const float* wkr = Wk + t * 256;
        const float* wvr = Wv + t * 256;
#pragma unroll 4
        for (int d = 0; d < 256; ++d) {
            uacc += wqr[d] * bk[d] + wkr[d] * bq[d];
            wvacc += wvr[d];
        }
        u[t] = uacc;
        wv[t] = wvacc;
        __shared__ float r1[256], r2[256];
        r1[t] = bq[t] * bk[t];
        r2[t] = bv[t];
        __syncthreads();
        for (int s = 128; s > 0; s >>= 1) {
            if (t < s) { r1[t] += r1[t + s]; r2[t] += r2[t + s]; }
            __syncthreads();
        }
        if (t == 0) { scl[0] = r1[0]; scl[1] = r2[0]; }
    }
}

// ---------------------------------------------------------------------------
// score kernel v2: 64 pixels per block, 4 waves, wave w owns cols [w*64,w*64+64)
// for ALL 64 rows. Full-K (256) x tile staged hi/lo in swizzled LDS once
// (2 barriers). B frags from L2-resident M. Epilogue dots read x from LDS.
// ---------------------------------------------------------------------------
__device__ __forceinline__ int swz(int row, int col) {
    // XOR-swizzle element index: spreads the 512B row stride across banks
    return row * 256 + (col ^ ((row & 7) << 3));
}

__global__ __launch_bounds__(256, 2) void score_kernel(
    const float* __restrict__ x,
    const bf16_t* __restrict__ Mh, const bf16_t* __restrict__ Ml,
    const float* __restrict__ u, const float* __restrict__ wvp,
    const float* __restrict__ scl,
    float* __restrict__ score, float* __restrict__ svout)
{
    __shared__ __align__(16) char smem[65536];
    bf16_t* Ah = (bf16_t*)smem;            // [64][256] swizzled, 32KB
    bf16_t* Al = Ah + 16384;               // [64][256] swizzled, 32KB
    float* redS = (float*)smem;            // overlay after bar2: [4][64]
    float* redV = redS + 256;              // [4][64]

    const int t = threadIdx.x;
    const int lane = t & 63;
    const int wid = t >> 6;        // wave 0..3
    const int l15 = lane & 15;
    const int lg = lane >> 4;      // 0..3
    const int pix0 = blockIdx.x * 64;
    const int wcol0 = wid * 64;

    // ---- stage x[pix0..pix0+64)[0..256) as bf16 hi/lo into swizzled LDS ----
#pragma unroll
    for (int i = 0; i < 16; ++i) {
        int chunk = i * 256 + t;            // 4096 float4-chunks
        int r = chunk >> 6;
        int c4 = (chunk & 63) << 2;
        float4 xv = *(const float4*)(x + (size_t)(pix0 + r) * 256 + c4);
        bf16x4 hi, lo;
        hi[0] = (bf16_t)xv.x; hi[1] = (bf16_t)xv.y;
        hi[2] = (bf16_t)xv.z; hi[3] = (bf16_t)xv.w;
        lo[0] = (bf16_t)(xv.x - (float)hi[0]);
        lo[1] = (bf16_t)(xv.y - (float)hi[1]);
        lo[2] = (bf16_t)(xv.z - (float)hi[2]);
        lo[3] = (bf16_t)(xv.w - (float)hi[3]);
        int idx = swz(r, c4);
        *(bf16x4*)&Ah[idx] = hi;
        *(bf16x4*)&Al[idx] = lo;
    }
    __syncthreads();   // bar1

    f32x4 acc[4][4];
#pragma unroll
    for (int i = 0; i < 4; ++i)
#pragma unroll
        for (int j = 0; j < 4; ++j)
            acc[i][j] = (f32x4){0.f, 0.f, 0.f, 0.f};

    // ---- MFMA sweep: K=256 in 8 steps of 32, 3 precision segments ----
#pragma unroll
    for (int ks = 0; ks < 8; ++ks) {
        const int k0 = ks * 32;
        bf16x8 af_h[4], af_l[4];
#pragma unroll
        for (int rf = 0; rf < 4; ++rf) {
            int row = rf * 16 + l15;
            int idx = swz(row, k0 + lg * 8);
            af_h[rf] = *(const bf16x8*)&Ah[idx];
            af_l[rf] = *(const bf16x8*)&Al[idx];
        }
        bf16x8 bfr_h[4], bfr_l[4];
#pragma unroll
        for (int cf = 0; cf < 4; ++cf) {
            int col = wcol0 + cf * 16 + l15;
            size_t boff = (size_t)col * 256 + k0 + lg * 8;
            bfr_h[cf] = *(const bf16x8*)(Mh + boff);
            bfr_l[cf] = *(const bf16x8*)(Ml + boff);
        }
#pragma unroll
        for (int rf = 0; rf < 4; ++rf)
#pragma unroll
            for (int cf = 0; cf < 4; ++cf)
                acc[rf][cf] = __builtin_amdgcn_mfma_f32_16x16x32_bf16(
                    af_h[rf], bfr_h[cf], acc[rf][cf], 0, 0, 0);
#pragma unroll
        for (int rf = 0; rf < 4; ++rf)
#pragma unroll
            for (int cf = 0; cf < 4; ++cf)
                acc[rf][cf] = __builtin_amdgcn_mfma_f32_16x16x32_bf16(
                    af_l[rf], bfr_h[cf], acc[rf][cf], 0, 0, 0);
#pragma unroll
        for (int rf = 0; rf < 4; ++rf)
#pragma unroll
            for (int cf = 0; cf < 4; ++cf)
                acc[rf][cf] = __builtin_amdgcn_mfma_f32_16x16x32_bf16(
                    af_h[rf], bfr_l[cf], acc[rf][cf], 0, 0, 0);
    }

    // ---- epilogue: s_p = sum_n x[p,n]*(Y[p,n]+u[n]); v_p = sum_n x[p,n]*wv[n]
    float uu[4], wvl[4];
#pragma unroll
    for (int cf = 0; cf < 4; ++cf) {
        uu[cf] = u[wcol0 + cf * 16 + l15];
        wvl[cf] = wvp[wcol0 + cf * 16 + l15];
    }
    float sacc[4][4], vacc[4][4];
#pragma unroll
    for (int rf = 0; rf < 4; ++rf) {
#pragma unroll
        for (int r = 0; r < 4; ++r) {
            int row = rf * 16 + lg * 4 + r;   // C layout: col=lane&15, row=(lane>>4)*4+reg
            float s = 0.f, v = 0.f;
#pragma unroll
            for (int cf = 0; cf < 4; ++cf) {
                int col = wcol0 + cf * 16 + l15;
                int idx = swz(row, col);
                float xv = (float)Ah[idx] + (float)Al[idx];
                s += xv * (acc[rf][cf][r] + uu[cf]);
                v += xv * wvl[cf];
            }
#pragma unroll
            for (int m = 1; m < 16; m <<= 1) {
                s += __shfl_xor(s, m, 64);
                v += __shfl_xor(v, m, 64);
            }
            sacc[rf][r] = s;
            vacc[rf][r] = v;
        }
    }
    __syncthreads();   // bar2: all LDS x-reads done; safe to overlay reductions
    if (l15 == 0) {
#pragma unroll
        for (int rf = 0; rf < 4; ++rf)
#pragma unroll
            for (int r = 0; r < 4; ++r) {
                int row = rf * 16 + lg * 4 + r;
                redS[wid * 64 + row] = sacc[rf][r];
                redV[wid * 64 + row] = vacc[rf][r];
            }
    }
    __syncthreads();   // bar3
    if (t < 64) {
        float c0 = scl[0], bvs = scl[1];
        float s = redS[t] + redS[64 + t] + redS[128 + t] + redS[192 + t] + c0;
        float v = redV[t] + redV[64 + t] + redV[128 + t] + redV[192 + t] + bvs;
        score[pix0 + t] = s;
        svout[pix0 + t] = v;
    }
}

// ---------------------------------------------------------------------------
// per-batch softmax stats over 4096 pixels
// ---------------------------------------------------------------------------
__global__ __launch_bounds__(256) void stats_kernel(
    const float* __restrict__ score,
    float* __restrict__ bmax, float* __restrict__ bsum)
{
    const int b = blockIdx.x, t = threadIdx.x;
    const float* s = score + b * PPB;
    __shared__ float red[256];
    float m = -1e30f;
    for (int i = t; i < PPB; i += 256) m = fmaxf(m, s[i]);
    red[t] = m;
    __syncthreads();
    for (int k = 128; k > 0; k >>= 1) {
        if (t < k) red[t] = fmaxf(red[t], red[t + k]);
        __syncthreads();
    }
    m = red[0];
    __syncthreads();
    float sum = 0.f;
    for (int i = t; i < PPB; i += 256) sum += __expf(s[i] - m);
    red[t] = sum;
    __syncthreads();
    for (int k = 128; k > 0; k >>= 1) {
        if (t < k) red[t] += red[t + k];
        __syncthreads();
    }
    if (t == 0) { bmax[b] = m; bsum[b] = red[0]; }
}

// ---------------------------------------------------------------------------
// output: out[p, 0:256] = g_p * Wo + bo,  g_p = softmax(score)_p * sv_p
// ---------------------------------------------------------------------------
__global__ __launch_bounds__(256) void out_kernel(
    const float* __restrict__ score, const float* __restrict__ sv,
    const float* __restrict__ bmax, const float* __restrict__ bsum,
    const float* __restrict__ Wo, const float* __restrict__ bo,
    float* __restrict__ out)
{
    const int total = NPIX * 64;  // float4 count
    const int stride = gridDim.x * blockDim.x;
    for (int idx = blockIdx.x * blockDim.x + threadIdx.x; idx < total; idx += stride) {
        int p = idx >> 6;
        int c4 = (idx & 63) << 2;
        int b = p >> 12;
        float g = __expf(score[p] - bmax[b]) / bsum[b] * sv[p];
        float4 w = *(const float4*)(Wo + c4);
        float4 bb = *(const float4*)(bo + c4);
        float4 o = { g * w.x + bb.x, g * w.y + bb.y, g * w.z + bb.z, g * w.w + bb.w };
        *(float4*)(out + (size_t)p * 256 + c4) = o;
    }
}

extern "C" void kernel_launch(void* const* d_in, const int* in_sizes, int n_in,
                              void* d_out, int out_size, void* d_ws, size_t ws_size,
                              hipStream_t stream) {
    const float* x  = (const float*)d_in[0];
    const float* Wq = (const float*)d_in[1];
    const float* bq = (const float*)d_in[2];
    const float* Wk = (const float*)d_in[3];
    const float* bk = (const float*)d_in[4];
    const float* Wv = (const float*)d_in[5];
    const float* bv = (const float*)d_in[6];
    const float* Wo = (const float*)d_in[7];
    const float* bo = (const float*)d_in[8];
    float* out = (float*)d_out;
    char* ws = (char*)d_ws;

    bf16_t* Mh = (bf16_t*)(ws + MH_OFF);
    bf16_t* Ml = (bf16_t*)(ws + ML_OFF);
    float* u   = (float*)(ws + U_OFF);
    float* wv  = (float*)(ws + WV_OFF);
    float* scl = (float*)(ws + SCL_OFF);
    float* score = (float*)(ws + SCORE_OFF);
    float* sv    = (float*)(ws + SV_OFF);
    float* bmax  = (float*)(ws + BMAX_OFF);
    float* bsum  = (float*)(ws + BSUM_OFF);

    prep_kernel<<<dim3(257), dim3(256), 0, stream>>>(Wq, bq, Wk, bk, Wv, bv, Mh, Ml, u, wv, scl);
    score_kernel<<<dim3(NPIX / 64), dim3(256), 0, stream>>>(x, Mh, Ml, u, wv, scl, score, sv);
    stats_kernel<<<dim3(NBATCH), dim3(256), 0, stream>>>(score, bmax, bsum);
    out_kernel<<<dim3(2048), dim3(256), 0, stream>>>(score, sv, bmax, bsum, Wo, bo, out);
}